// Round 18
// baseline (175.535 us; speedup 1.0000x reference)
//
#include <hip/hip_runtime.h>
#include <math.h>

#define N_NODES 10000
#define N_EDGES 160000
#define ET      (N_EDGES + N_NODES)   // with self loops
#define NRG     313                   // ceil(10000/32) row groups (mmP packing)
#define AZS     ((size_t)NRG * 4096)  // u16 per K=128 A-pack

typedef unsigned short u16;
typedef __attribute__((ext_vector_type(8))) short bf16x8;
typedef __attribute__((ext_vector_type(4))) float f32x4;

__device__ __forceinline__ u16 f2bf(float f) {            // RNE
    union { float f; unsigned u; } v; v.f = f;
    unsigned r = (v.u + 0x7FFFu + ((v.u >> 16) & 1u)) >> 16;
    return (u16)r;
}
__device__ __forceinline__ float bf2f(u16 b) {
    union { unsigned u; float f; } v; v.u = ((unsigned)b) << 16;
    return v.f;
}

__device__ __forceinline__ void split1(float f, u16& h, u16& l) {
    unsigned u = __float_as_uint(f);
    h = (u16)(u >> 16);
    l = f2bf(f - __uint_as_float(u & 0xffff0000u));
}

__device__ __forceinline__ void splitA8(const float* __restrict__ p,
                                        bf16x8& hv, bf16x8& lv) {
    float4 v0 = *reinterpret_cast<const float4*>(p);
    float4 v1 = *reinterpret_cast<const float4*>(p + 4);
    float f[8] = {v0.x, v0.y, v0.z, v0.w, v1.x, v1.y, v1.z, v1.w};
    bf16x8 h, l;
#pragma unroll
    for (int i = 0; i < 8; ++i) {
        unsigned u = __float_as_uint(f[i]);
        h[i] = (short)(u >> 16);
        float r = f[i] - __uint_as_float(u & 0xffff0000u);
        l[i] = (short)(__float_as_uint(r) >> 16);
    }
    hv = h; lv = l;
}

// fragment-pack offset for K=128 A operand: (row, k) -> u16 index
__device__ __forceinline__ size_t packA_off(int row, int k) {
    int rg = row >> 5, fm = (row >> 4) & 1, lr = row & 15;
    int kb = k >> 5, q = (k >> 3) & 3, j = k & 7;
    return ((((size_t)rg * 4 + kb) * 2 + fm) * 64 + q * 16 + lr) * 8 + j;
}

#define MFMA3(A_h, A_l, B_h, B_l, ACC)                                            \
    ACC = __builtin_amdgcn_mfma_f32_16x16x32_bf16(A_h, B_h, ACC, 0, 0, 0);        \
    ACC = __builtin_amdgcn_mfma_f32_16x16x32_bf16(A_h, B_l, ACC, 0, 0, 0);        \
    ACC = __builtin_amdgcn_mfma_f32_16x16x32_bf16(A_l, B_h, ACC, 0, 0, 0);

#define GLD16(SRC, DST)                                                           \
    __builtin_amdgcn_global_load_lds(                                             \
        (const __attribute__((address_space(1))) void*)(SRC),                     \
        (__attribute__((address_space(3))) void*)(DST), 16, 0, 0)

// ---------------------------------------------------------------------------
// Fused prep: blocks 0..159 wpack all 4 weights; block 160 va1; 161..200 zero deg.
// ---------------------------------------------------------------------------
__global__ void prep_kernel(const float* __restrict__ W0, u16* p0h, u16* p0l,
                            const float* __restrict__ W1, u16* p1h, u16* p1l,
                            const float* __restrict__ W2, u16* p2h, u16* p2l,
                            const float* __restrict__ W3, u16* p3h, u16* p3l,
                            const float* __restrict__ att_src,
                            const float* __restrict__ att_dst,
                            float* __restrict__ vas, float* __restrict__ vad,
                            int* __restrict__ deg) {
    int b = blockIdx.x, tid = threadIdx.x;
    if (b < 160) {
        int idx = b * 256 + tid;
        const float* W; u16 *oh, *ol; int K, N, rel;
        if      (idx < 12288) { W = W0; oh = p0h; ol = p0l; K = 768; N = 128; rel = idx; }
        else if (idx < 20480) { W = W1; oh = p1h; ol = p1l; K = 128; N = 512; rel = idx - 12288; }
        else if (idx < 28672) { W = W2; oh = p2h; ol = p2l; K = 512; N = 128; rel = idx - 20480; }
        else                  { W = W3; oh = p3h; ol = p3l; K = 128; N = 768; rel = idx - 28672; }
        int perCg = (K / 32) * 128;
        int cg = rel / perCg, r2 = rel - cg * perCg;
        int kb = r2 >> 7, r3 = r2 & 127;
        int fn = r3 >> 6, lane = r3 & 63;
        int col = cg * 32 + fn * 16 + (lane & 15);
        int k0  = kb * 32 + (lane >> 4) * 8;
        bf16x8 hv, lv;
#pragma unroll
        for (int j = 0; j < 8; ++j) {
            float v = W[(size_t)(k0 + j) * N + col];
            u16 h = f2bf(v);
            hv[j] = (short)h;
            lv[j] = (short)f2bf(v - bf2f(h));
        }
        *(bf16x8*)(oh + (size_t)rel * 8) = hv;
        *(bf16x8*)(ol + (size_t)rel * 8) = lv;
    } else if (b == 160) {
        for (int it = tid; it < 512; it += 256) {
            int k = it >> 2, h = it & 3;
            float s = 0.0f, d = 0.0f;
            const float* wr = W1 + (size_t)k * 512 + h * 128;
            const float* as = att_src + h * 128;
            const float* ad = att_dst + h * 128;
            for (int c = 0; c < 128; ++c) {
                float w = wr[c];
                s = fmaf(w, as[c], s);
                d = fmaf(w, ad[c], d);
            }
            vas[k * 4 + h] = s;
            vad[k * 4 + h] = d;
        }
    } else {
        int i = (b - 161) * 256 + tid;
        if (i < N_NODES) deg[i] = 0;
    }
}

// ---------------------------------------------------------------------------
// LDS-pipelined split-bf16 GEMM, BK=128 (half the barriers of BK=64).
// 32 rows x 128 cols per block, 4 waves; A staged via global_load_lds into
// 16 groups of [32 rows][8 k] (260-float stride, conflict-free, proven);
// B fragment-packed, loaded per stage (L2-hot).
// ATTH: 0=none; 4=fused a1s/a1d logits (z==0); 1=fused a2s/a2d.
// ---------------------------------------------------------------------------
template<int K, int SRCSEL, int ZC, int ACT, int LDOUT, int ATTH>
__global__ __launch_bounds__(256)
void mmT_kernel(const float* __restrict__ A0, const float* __restrict__ A1,
                size_t azs,
                const u16* __restrict__ Bh, const u16* __restrict__ Bl,
                const float* __restrict__ bias,
                float* __restrict__ out0, float* __restrict__ out1,
                const float* __restrict__ attVs, const float* __restrict__ attVd,
                float* __restrict__ attS, float* __restrict__ attD) {
    constexpr int NS = K / 128;
    __shared__ float smem[2 * 4160];           // 2 buffers x 16 groups x 260
    __shared__ float ared[4][32][8];
    const int lane = threadIdx.x & 63;
    const int wid  = threadIdx.x >> 6;
    const int lr = lane & 15, q = lane >> 4;
    const int row0 = blockIdx.x * 32;
    const int z = blockIdx.z;
    const int gcb = blockIdx.y * 128 + z * ZC;

    const float* Ab = SRCSEL ? (z ? A1 : A0) : (A0 + (size_t)z * azs);
    float* outp = (SRCSEL && z) ? out1 : out0;

    const int srow = min(row0 + (lane >> 1), N_NODES - 1);
    const float* sA = Ab + (size_t)srow * K + (lane & 1) * 4;

    const int cg = gcb / 32 + wid;
    const u16* pbh = Bh + (size_t)cg * K * 32 + lane * 8;
    const u16* pbl = Bl + (size_t)cg * K * 32 + lane * 8;

    f32x4 acc[2][2];
#pragma unroll
    for (int i = 0; i < 2; ++i)
#pragma unroll
        for (int j = 0; j < 2; ++j) acc[i][j] = (f32x4){0.f, 0.f, 0.f, 0.f};

    // stage S into buffer BUF: wave wid stages groups wid*4 .. wid*4+3
#define STAGE_T(BUF, S) do {                                                   \
        float* dgb = smem + (BUF) * 4160 + (wid * 4) * 260;                    \
        GLD16(sA + (S) * 128 + (wid * 4 + 0) * 8, dgb + 0 * 260);              \
        GLD16(sA + (S) * 128 + (wid * 4 + 1) * 8, dgb + 1 * 260);              \
        GLD16(sA + (S) * 128 + (wid * 4 + 2) * 8, dgb + 2 * 260);              \
        GLD16(sA + (S) * 128 + (wid * 4 + 3) * 8, dgb + 3 * 260);              \
    } while (0)

    STAGE_T(0, 0);
    __syncthreads();

#pragma unroll
    for (int s = 0; s < NS; ++s) {
        const int bank = s & 1;
        if (s + 1 < NS) STAGE_T(bank ^ 1, s + 1);

        // B fragments for this stage (coalesced lane*16B, L2-hot)
        bf16x8 rbh[2][4], rbl[2][4];           // [fn][ks]
#pragma unroll
        for (int fn = 0; fn < 2; ++fn)
#pragma unroll
            for (int ks = 0; ks < 4; ++ks) {
                rbh[fn][ks] = *(const bf16x8*)(pbh + (((s * 4 + ks) * 2 + fn)) * 512);
                rbl[fn][ks] = *(const bf16x8*)(pbl + (((s * 4 + ks) * 2 + fn)) * 512);
            }

        const float* lb = smem + bank * 4160;
#pragma unroll
        for (int ks = 0; ks < 4; ++ks) {
            bf16x8 ah[2], al[2];
#pragma unroll
            for (int fm = 0; fm < 2; ++fm) {
                const float* fp = lb + (ks * 4 + q) * 260 + (fm * 16 + lr) * 8;
                splitA8(fp, ah[fm], al[fm]);
            }
#pragma unroll
            for (int fm = 0; fm < 2; ++fm) {
                MFMA3(ah[fm], al[fm], rbh[0][ks], rbl[0][ks], acc[fm][0]);
                MFMA3(ah[fm], al[fm], rbh[1][ks], rbl[1][ks], acc[fm][1]);
            }
        }
        __syncthreads();
    }

    // epilogue: rv = acc + bias (pre-activation), store, then fused logits
    float rv[2][2][4];
    int orq = q * 4;
#pragma unroll
    for (int fm = 0; fm < 2; ++fm)
#pragma unroll
        for (int fn = 0; fn < 2; ++fn) {
            int col = gcb + wid * 32 + fn * 16 + lr;
            float bb = bias ? bias[col] : 0.0f;
#pragma unroll
            for (int i = 0; i < 4; ++i) {
                float r = acc[fm][fn][i] + bb;
                rv[fm][fn][i] = r;
                int orow = row0 + fm * 16 + orq + i;
                if (orow < N_NODES) {
                    if (ACT == 1) r = r > 0.0f ? r : expm1f(r);
                    outp[(size_t)orow * LDOUT + col] = r;
                }
            }
        }

    if (ATTH == 4) {
        if (z == 0) {
            const float4 vs0 = *reinterpret_cast<const float4*>(attVs + (wid * 32 + lr) * 4);
            const float4 vs1 = *reinterpret_cast<const float4*>(attVs + (wid * 32 + 16 + lr) * 4);
            const float4 vd0 = *reinterpret_cast<const float4*>(attVd + (wid * 32 + lr) * 4);
            const float4 vd1 = *reinterpret_cast<const float4*>(attVd + (wid * 32 + 16 + lr) * 4);
#pragma unroll
            for (int fm = 0; fm < 2; ++fm)
#pragma unroll
                for (int i = 0; i < 4; ++i) {
                    float r0 = rv[fm][0][i], r1 = rv[fm][1][i];
                    float ps[4] = { r0 * vs0.x + r1 * vs1.x, r0 * vs0.y + r1 * vs1.y,
                                    r0 * vs0.z + r1 * vs1.z, r0 * vs0.w + r1 * vs1.w };
                    float pd[4] = { r0 * vd0.x + r1 * vd1.x, r0 * vd0.y + r1 * vd1.y,
                                    r0 * vd0.z + r1 * vd1.z, r0 * vd0.w + r1 * vd1.w };
#pragma unroll
                    for (int m = 1; m < 16; m <<= 1)
#pragma unroll
                        for (int h = 0; h < 4; ++h) {
                            ps[h] += __shfl_xor(ps[h], m, 64);
                            pd[h] += __shfl_xor(pd[h], m, 64);
                        }
                    if (lr == 0) {
                        int rloc = fm * 16 + orq + i;
#pragma unroll
                        for (int h = 0; h < 4; ++h) {
                            ared[wid][rloc][h]     = ps[h];
                            ared[wid][rloc][4 + h] = pd[h];
                        }
                    }
                }
            __syncthreads();
            int rloc = threadIdx.x >> 3, sl = threadIdx.x & 7;
            float v = ared[0][rloc][sl] + ared[1][rloc][sl] +
                      ared[2][rloc][sl] + ared[3][rloc][sl];
            int orow = row0 + rloc;
            if (orow < N_NODES) {
                if (sl < 4) attS[(size_t)orow * 4 + sl] = v;
                else        attD[(size_t)orow * 4 + (sl - 4)] = v;
            }
        }
    } else if (ATTH == 1) {
        float vs0 = attVs[wid * 32 + lr], vs1 = attVs[wid * 32 + 16 + lr];
        float vd0 = attVd[wid * 32 + lr], vd1 = attVd[wid * 32 + 16 + lr];
#pragma unroll
        for (int fm = 0; fm < 2; ++fm)
#pragma unroll
            for (int i = 0; i < 4; ++i) {
                float r0 = rv[fm][0][i], r1 = rv[fm][1][i];
                float ps = r0 * vs0 + r1 * vs1;
                float pd = r0 * vd0 + r1 * vd1;
#pragma unroll
                for (int m = 1; m < 16; m <<= 1) {
                    ps += __shfl_xor(ps, m, 64);
                    pd += __shfl_xor(pd, m, 64);
                }
                if (lr == 0) {
                    int rloc = fm * 16 + orq + i;
                    ared[wid][rloc][0] = ps;
                    ared[wid][rloc][1] = pd;
                }
            }
        __syncthreads();
        if (threadIdx.x < 64) {
            int rloc = threadIdx.x >> 1, sl = threadIdx.x & 1;
            float v = ared[0][rloc][sl] + ared[1][rloc][sl] +
                      ared[2][rloc][sl] + ared[3][rloc][sl];
            int orow = row0 + rloc;
            if (orow < N_NODES) {
                if (sl == 0) attS[orow] = v;
                else         attD[orow] = v;
            }
        }
    }
#undef STAGE_T
}

// ---------------------------------------------------------------------------
// Barrier-free packed-A / packed-B GEMM, K=128 (mm_head & decoder).
// ---------------------------------------------------------------------------
template<int ZC, int ACT, int LDOUT>
__global__ __launch_bounds__(256)
void mmP_kernel(const u16* __restrict__ Ah, const u16* __restrict__ Al,
                size_t azs,
                const u16* __restrict__ Bh, const u16* __restrict__ Bl,
                const float* __restrict__ bias,
                float* __restrict__ out) {
    constexpr int K = 128;
    const int lane = threadIdx.x & 63;
    const int wid  = threadIdx.x >> 6;
    const int lr = lane & 15, q = lane >> 4;
    const int rg = blockIdx.x;
    const int row0 = rg * 32;
    const int z = blockIdx.z;
    const int gcb = blockIdx.y * 128 + z * ZC;

    const u16* ah = Ah + (size_t)z * azs + (size_t)rg * 4096 + lane * 8;
    const u16* al = Al + (size_t)z * azs + (size_t)rg * 4096 + lane * 8;
    const int cg = gcb / 32 + wid;
    const u16* bh = Bh + (size_t)cg * K * 32 + lane * 8;
    const u16* bl = Bl + (size_t)cg * K * 32 + lane * 8;

    f32x4 acc[2][2];
#pragma unroll
    for (int i = 0; i < 2; ++i)
#pragma unroll
        for (int j = 0; j < 2; ++j) acc[i][j] = (f32x4){0.f, 0.f, 0.f, 0.f};

#pragma unroll
    for (int kb = 0; kb < 4; ++kb) {
        bf16x8 a0h = *(const bf16x8*)(ah + (kb * 2 + 0) * 512);
        bf16x8 a1h = *(const bf16x8*)(ah + (kb * 2 + 1) * 512);
        bf16x8 a0l = *(const bf16x8*)(al + (kb * 2 + 0) * 512);
        bf16x8 a1l = *(const bf16x8*)(al + (kb * 2 + 1) * 512);
        bf16x8 b0h = *(const bf16x8*)(bh + (kb * 2 + 0) * 512);
        bf16x8 b1h = *(const bf16x8*)(bh + (kb * 2 + 1) * 512);
        bf16x8 b0l = *(const bf16x8*)(bl + (kb * 2 + 0) * 512);
        bf16x8 b1l = *(const bf16x8*)(bl + (kb * 2 + 1) * 512);
        MFMA3(a0h, a0l, b0h, b0l, acc[0][0]);
        MFMA3(a0h, a0l, b1h, b1l, acc[0][1]);
        MFMA3(a1h, a1l, b0h, b0l, acc[1][0]);
        MFMA3(a1h, a1l, b1h, b1l, acc[1][1]);
    }

    int orq = q * 4;
#pragma unroll
    for (int fm = 0; fm < 2; ++fm)
#pragma unroll
        for (int fn = 0; fn < 2; ++fn) {
            int col = gcb + wid * 32 + fn * 16 + lr;
            float bb = bias[col];
#pragma unroll
            for (int i = 0; i < 4; ++i) {
                int orow = row0 + fm * 16 + orq + i;
                if (orow < N_NODES) {
                    float r = acc[fm][fn][i] + bb;
                    if (ACT == 1) r = r > 0.0f ? r : expm1f(r);
                    out[(size_t)orow * LDOUT + col] = r;
                }
            }
        }
}

// ---------------------------------------------------------------------------
// CSR build
// ---------------------------------------------------------------------------
__global__ void deg_kernel(const int* __restrict__ ei, int* __restrict__ deg) {
    int e = blockIdx.x * blockDim.x + threadIdx.x;
    if (e >= ET) return;
    int d = (e < N_EDGES) ? ei[N_EDGES + e] : (e - N_EDGES);
    atomicAdd(&deg[d], 1);
}

__global__ void scan1_kernel(const int* __restrict__ deg, int* __restrict__ bsum) {
    __shared__ int sm[256];
    int i = blockIdx.x * 256 + threadIdx.x;
    sm[threadIdx.x] = (i < N_NODES) ? deg[i] : 0;
    __syncthreads();
    for (int s = 128; s > 0; s >>= 1) {
        if (threadIdx.x < s) sm[threadIdx.x] += sm[threadIdx.x + s];
        __syncthreads();
    }
    if (threadIdx.x == 0) bsum[blockIdx.x] = sm[0];
}

__global__ void scan3_kernel(const int* __restrict__ deg, const int* __restrict__ bsum,
                             int* __restrict__ off, int* __restrict__ cur) {
    __shared__ int sm[256];
    __shared__ int sb[40];
    __shared__ int bofs;
    int tid = threadIdx.x;
    if (tid < 40) sb[tid] = bsum[tid];
    int i = blockIdx.x * 256 + tid;
    int v = (i < N_NODES) ? deg[i] : 0;
    sm[tid] = v;
    __syncthreads();
    if (tid == 0) {
        int s = 0;
        for (int b = 0; b < blockIdx.x; ++b) s += sb[b];
        bofs = s;
    }
    for (int s = 1; s < 256; s <<= 1) {
        int t = (tid >= s) ? sm[tid - s] : 0;
        __syncthreads();
        sm[tid] += t;
        __syncthreads();
    }
    if (i < N_NODES) {
        int ex = bofs + sm[tid] - v;
        off[i] = ex;
        cur[i] = ex;
    }
    if (blockIdx.x == 0 && tid == 0) off[N_NODES] = ET;
}

__global__ void fill_kernel(const int* __restrict__ ei,
                            int* __restrict__ cur, int* __restrict__ csr_src) {
    int e = blockIdx.x * blockDim.x + threadIdx.x;
    if (e >= ET) return;
    int s, d;
    if (e < N_EDGES) { s = ei[e]; d = ei[N_EDGES + e]; }
    else             { s = e - N_EDGES; d = s; }
    int pos = atomicAdd(&cur[d], 1);
    csr_src[pos] = s;
}

// ---------------------------------------------------------------------------
// Fused softmax + aggregation, layer 1 (H=4), SINGLE PASS.
// ---------------------------------------------------------------------------
__global__ __launch_bounds__(128)
void smagg1_kernel(const float* __restrict__ xp,
                   const float* __restrict__ a1s, const float* __restrict__ a1d,
                   const int* __restrict__ off, const int* __restrict__ csr,
                   u16* __restrict__ aggPh, u16* __restrict__ aggPl) {
    int n = blockIdx.x;
    int tid = threadIdx.x;
    int o0 = off[n], o1 = off[n + 1];
    __shared__ float wsh[128][4];
    __shared__ int   ssh[128];

    float4 adv = *reinterpret_cast<const float4*>(a1d + (size_t)n * 4);
    float adn[4] = {adv.x, adv.y, adv.z, adv.w};

    float a0 = 0.f, a1 = 0.f, a2 = 0.f, a3 = 0.f;
    float s0 = 0.f, s1 = 0.f, s2 = 0.f, s3 = 0.f;
    for (int base = o0; base < o1; base += 128) {
        __syncthreads();
        int j = base + tid;
        if (j < o1) {
            int sn = csr[j];
            ssh[tid] = sn;
            float4 asv = *reinterpret_cast<const float4*>(a1s + (size_t)sn * 4);
            float e0 = asv.x + adn[0]; e0 = e0 > 0.f ? e0 : 0.2f * e0; wsh[tid][0] = expf(e0);
            float e1 = asv.y + adn[1]; e1 = e1 > 0.f ? e1 : 0.2f * e1; wsh[tid][1] = expf(e1);
            float e2 = asv.z + adn[2]; e2 = e2 > 0.f ? e2 : 0.2f * e2; wsh[tid][2] = expf(e2);
            float e3 = asv.w + adn[3]; e3 = e3 > 0.f ? e3 : 0.2f * e3; wsh[tid][3] = expf(e3);
        }
        __syncthreads();
        int cnt = min(128, o1 - base);
        for (int e2i = 0; e2i < cnt; ++e2i) {
            float v = xp[(size_t)ssh[e2i] * 128 + tid];
            float4 w = *reinterpret_cast<const float4*>(&wsh[e2i][0]);
            a0 = fmaf(w.x, v, a0); s0 += w.x;
            a1 = fmaf(w.y, v, a1); s1 += w.y;
            a2 = fmaf(w.z, v, a2); s2 += w.z;
            a3 = fmaf(w.w, v, a3); s3 += w.w;
        }
    }

    float r[4] = {a0 / (s0 + 1e-16f), a1 / (s1 + 1e-16f),
                  a2 / (s2 + 1e-16f), a3 / (s3 + 1e-16f)};
    size_t po = packA_off(n, tid);
#pragma unroll
    for (int h = 0; h < 4; ++h) {
        u16 hi, lo;
        split1(r[h], hi, lo);
        aggPh[(size_t)h * AZS + po] = hi;
        aggPl[(size_t)h * AZS + po] = lo;
    }
}

// ---------------------------------------------------------------------------
// Fused softmax + gather, layer 2 (H=1), SINGLE PASS, + bias + beta*gp.
// ---------------------------------------------------------------------------
__global__ __launch_bounds__(128)
void smgather2_kernel(const float* __restrict__ h2,
                      const float* __restrict__ a2s, const float* __restrict__ a2d,
                      const int* __restrict__ off, const int* __restrict__ csr,
                      const float* __restrict__ bias,
                      u16* __restrict__ outPh, u16* __restrict__ outPl,
                      const float* __restrict__ gp,
                      const float* __restrict__ beta_p) {
    int n = blockIdx.x;
    int tid = threadIdx.x;
    int o0 = off[n], o1 = off[n + 1];
    __shared__ float wsh[128];
    __shared__ int   ssh[128];

    float adn = a2d[n];
    float acc = 0.f, s = 0.f;
    for (int base = o0; base < o1; base += 128) {
        __syncthreads();
        int j = base + tid;
        if (j < o1) {
            int sn = csr[j];
            ssh[tid] = sn;
            float e = a2s[sn] + adn;
            e = e > 0.f ? e : 0.2f * e;
            wsh[tid] = expf(e);
        }
        __syncthreads();
        int cnt = min(128, o1 - base);
        for (int e2i = 0; e2i < cnt; ++e2i) {
            float w = wsh[e2i];
            acc = fmaf(w, h2[(size_t)ssh[e2i] * 128 + tid], acc);
            s += w;
        }
    }

    float r = acc / (s + 1e-16f) + bias[tid] + beta_p[0] * gp[(size_t)n * 128 + tid];
    u16 hi, lo;
    split1(r, hi, lo);
    size_t po = packA_off(n, tid);
    outPh[po] = hi;
    outPl[po] = lo;
}

// ---------------------------------------------------------------------------
extern "C" void kernel_launch(void* const* d_in, const int* in_sizes, int n_in,
                              void* d_out, int out_size, void* d_ws, size_t ws_size,
                              hipStream_t stream) {
    const float* x      = (const float*)d_in[0];
    const int*   ei     = (const int*)  d_in[1];
    const float* g      = (const float*)d_in[2];
    const float* proj_W = (const float*)d_in[3];
    const float* proj_b = (const float*)d_in[4];
    const float* gat1_W = (const float*)d_in[5];
    const float* g1_as  = (const float*)d_in[6];
    const float* g1_ad  = (const float*)d_in[7];
    const float* gat1_b = (const float*)d_in[8];
    const float* gat2_W = (const float*)d_in[9];
    const float* g2_as  = (const float*)d_in[10];
    const float* g2_ad  = (const float*)d_in[11];
    const float* gat2_b = (const float*)d_in[12];
    const float* dec_W  = (const float*)d_in[13];
    const float* dec_b  = (const float*)d_in[14];
    const float* beta   = (const float*)d_in[15];
    float* out = (float*)d_out;

    // ---- workspace carve ----
    char* p = (char*)d_ws;
    auto alloc = [&](size_t b) { void* r = (void*)p; p += (b + 255) & ~(size_t)255; return r; };
    float* helu  = (float*)alloc((size_t)10000 * 512 * 4);
    u16*   aggPh = (u16*)alloc(4 * AZS * 2);
    u16*   aggPl = (u16*)alloc(4 * AZS * 2);
    u16*   hfPh  = (u16*)alloc(AZS * 2);
    u16*   hfPl  = (u16*)alloc(AZS * 2);
    float* xp    = (float*)alloc((size_t)10000 * 128 * 4);     // h2 alias
    float* gp    = (float*)alloc((size_t)10000 * 128 * 4);
    u16*   pwh   = (u16*)alloc(768 * 128 * 2);
    u16*   pwl   = (u16*)alloc(768 * 128 * 2);
    u16*   w1h   = (u16*)alloc(128 * 512 * 2);
    u16*   w1l   = (u16*)alloc(128 * 512 * 2);
    u16*   w2h   = (u16*)alloc(512 * 128 * 2);
    u16*   w2l   = (u16*)alloc(512 * 128 * 2);
    u16*   wdh   = (u16*)alloc(128 * 768 * 2);
    u16*   wdl   = (u16*)alloc(128 * 768 * 2);
    float* va1s  = (float*)alloc(128 * 4 * 4);
    float* va1d  = (float*)alloc(128 * 4 * 4);
    float* a1s   = (float*)alloc((size_t)N_NODES * 4 * 4);
    float* a1d   = (float*)alloc((size_t)N_NODES * 4 * 4);
    float* a2s   = (float*)alloc((size_t)N_NODES * 4);
    float* a2d   = (float*)alloc((size_t)N_NODES * 4);
    int*   deg   = (int*)alloc((size_t)N_NODES * 4);
    int*   off   = (int*)alloc((size_t)(N_NODES + 1) * 4);
    int*   cur   = (int*)alloc((size_t)N_NODES * 4);
    int*   csr   = (int*)alloc((size_t)ET * 4);
    int*   bsum  = (int*)alloc(64 * 4);
    // aliases
    float* h2 = xp;

    // ---- fused prep (wpack + va1 + deg zero) ----
    hipLaunchKernelGGL(prep_kernel, dim3(201), dim3(256), 0, stream,
                       proj_W, pwh, pwl, gat1_W, w1h, w1l,
                       gat2_W, w2h, w2l, dec_W, wdh, wdl,
                       g1_as, g1_ad, va1s, va1d, deg);
    hipLaunchKernelGGL(deg_kernel, dim3((ET + 255) / 256), dim3(256), 0, stream, ei, deg);
    hipLaunchKernelGGL(scan1_kernel, dim3(40), dim3(256), 0, stream, deg, bsum);
    hipLaunchKernelGGL(scan3_kernel, dim3(40), dim3(256), 0, stream, deg, bsum, off, cur);
    hipLaunchKernelGGL(fill_kernel, dim3((ET + 255) / 256), dim3(256), 0, stream, ei, cur, csr);

    // ---- proj: xp = x@Wp+b, gp = g@Wp+b; logits a1s/a1d fused (z==0) ----
    hipLaunchKernelGGL((mmT_kernel<768, 1, 0, 0, 128, 4>), dim3(NRG, 1, 2), dim3(256), 0, stream,
                       x, g, (size_t)0, pwh, pwl, proj_b, xp, gp,
                       va1s, va1d, a1s, a1d);

    // ---- gat1 ----
    hipLaunchKernelGGL(smagg1_kernel, dim3(N_NODES), dim3(128), 0, stream,
                       xp, a1s, a1d, off, csr, aggPh, aggPl);
    hipLaunchKernelGGL((mmP_kernel<128, 1, 512>), dim3(NRG, 1, 4), dim3(256), 0, stream,
                       aggPh, aggPl, AZS, w1h, w1l, gat1_b, helu);

    // ---- gat2: h2 = helu @ W2; logits a2s/a2d fused ----
    hipLaunchKernelGGL((mmT_kernel<512, 0, 0, 0, 128, 1>), dim3(NRG, 1, 1), dim3(256), 0, stream,
                       helu, (const float*)nullptr, (size_t)0,
                       w2h, w2l, (const float*)nullptr, h2, (float*)nullptr,
                       g2_as, g2_ad, a2s, a2d);
    hipLaunchKernelGGL(smgather2_kernel, dim3(N_NODES), dim3(128), 0, stream,
                       h2, a2s, a2d, off, csr, gat2_b, hfPh, hfPl, gp, beta);

    // ---- decoder ----
    hipLaunchKernelGGL((mmP_kernel<0, 0, 768>), dim3(NRG, 6, 1), dim3(256), 0, stream,
                       hfPh, hfPl, (size_t)0, wdh, wdl, dec_b, out);
}

// Round 19
// 166.277 us; speedup vs baseline: 1.0557x; 1.0557x over previous
//
#include <hip/hip_runtime.h>
#include <math.h>

#define N_NODES 10000
#define N_EDGES 160000
#define ET      (N_EDGES + N_NODES)   // with self loops
#define NRG     313                   // ceil(10000/32) row groups (mmP packing)
#define AZS     ((size_t)NRG * 4096)  // u16 per K=128 A-pack

typedef unsigned short u16;
typedef __attribute__((ext_vector_type(8))) short bf16x8;
typedef __attribute__((ext_vector_type(4))) float f32x4;

__device__ __forceinline__ u16 f2bf(float f) {            // RNE
    union { float f; unsigned u; } v; v.f = f;
    unsigned r = (v.u + 0x7FFFu + ((v.u >> 16) & 1u)) >> 16;
    return (u16)r;
}
__device__ __forceinline__ float bf2f(u16 b) {
    union { unsigned u; float f; } v; v.u = ((unsigned)b) << 16;
    return v.f;
}

__device__ __forceinline__ void split1(float f, u16& h, u16& l) {
    unsigned u = __float_as_uint(f);
    h = (u16)(u >> 16);
    l = f2bf(f - __uint_as_float(u & 0xffff0000u));
}

__device__ __forceinline__ void splitA8(const float* __restrict__ p,
                                        bf16x8& hv, bf16x8& lv) {
    float4 v0 = *reinterpret_cast<const float4*>(p);
    float4 v1 = *reinterpret_cast<const float4*>(p + 4);
    float f[8] = {v0.x, v0.y, v0.z, v0.w, v1.x, v1.y, v1.z, v1.w};
    bf16x8 h, l;
#pragma unroll
    for (int i = 0; i < 8; ++i) {
        unsigned u = __float_as_uint(f[i]);
        h[i] = (short)(u >> 16);
        float r = f[i] - __uint_as_float(u & 0xffff0000u);
        l[i] = (short)(__float_as_uint(r) >> 16);
    }
    hv = h; lv = l;
}

// fragment-pack offset for K=128 A operand: (row, k) -> u16 index
__device__ __forceinline__ size_t packA_off(int row, int k) {
    int rg = row >> 5, fm = (row >> 4) & 1, lr = row & 15;
    int kb = k >> 5, q = (k >> 3) & 3, j = k & 7;
    return ((((size_t)rg * 4 + kb) * 2 + fm) * 64 + q * 16 + lr) * 8 + j;
}

#define MFMA3(A_h, A_l, B_h, B_l, ACC)                                            \
    ACC = __builtin_amdgcn_mfma_f32_16x16x32_bf16(A_h, B_h, ACC, 0, 0, 0);        \
    ACC = __builtin_amdgcn_mfma_f32_16x16x32_bf16(A_h, B_l, ACC, 0, 0, 0);        \
    ACC = __builtin_amdgcn_mfma_f32_16x16x32_bf16(A_l, B_h, ACC, 0, 0, 0);

#define GLD16(SRC, DST)                                                           \
    __builtin_amdgcn_global_load_lds(                                             \
        (const __attribute__((address_space(1))) void*)(SRC),                     \
        (__attribute__((address_space(3))) void*)(DST), 16, 0, 0)

// ---------------------------------------------------------------------------
// Fused prep: blocks 0..159 wpack all 4 weights; block 160 va1; 161..200 zero deg.
// ---------------------------------------------------------------------------
__global__ void prep_kernel(const float* __restrict__ W0, u16* p0h, u16* p0l,
                            const float* __restrict__ W1, u16* p1h, u16* p1l,
                            const float* __restrict__ W2, u16* p2h, u16* p2l,
                            const float* __restrict__ W3, u16* p3h, u16* p3l,
                            const float* __restrict__ att_src,
                            const float* __restrict__ att_dst,
                            float* __restrict__ vas, float* __restrict__ vad,
                            int* __restrict__ deg) {
    int b = blockIdx.x, tid = threadIdx.x;
    if (b < 160) {
        int idx = b * 256 + tid;
        const float* W; u16 *oh, *ol; int K, N, rel;
        if      (idx < 12288) { W = W0; oh = p0h; ol = p0l; K = 768; N = 128; rel = idx; }
        else if (idx < 20480) { W = W1; oh = p1h; ol = p1l; K = 128; N = 512; rel = idx - 12288; }
        else if (idx < 28672) { W = W2; oh = p2h; ol = p2l; K = 512; N = 128; rel = idx - 20480; }
        else                  { W = W3; oh = p3h; ol = p3l; K = 128; N = 768; rel = idx - 28672; }
        int perCg = (K / 32) * 128;
        int cg = rel / perCg, r2 = rel - cg * perCg;
        int kb = r2 >> 7, r3 = r2 & 127;
        int fn = r3 >> 6, lane = r3 & 63;
        int col = cg * 32 + fn * 16 + (lane & 15);
        int k0  = kb * 32 + (lane >> 4) * 8;
        bf16x8 hv, lv;
#pragma unroll
        for (int j = 0; j < 8; ++j) {
            float v = W[(size_t)(k0 + j) * N + col];
            u16 h = f2bf(v);
            hv[j] = (short)h;
            lv[j] = (short)f2bf(v - bf2f(h));
        }
        *(bf16x8*)(oh + (size_t)rel * 8) = hv;
        *(bf16x8*)(ol + (size_t)rel * 8) = lv;
    } else if (b == 160) {
        for (int it = tid; it < 512; it += 256) {
            int k = it >> 2, h = it & 3;
            float s = 0.0f, d = 0.0f;
            const float* wr = W1 + (size_t)k * 512 + h * 128;
            const float* as = att_src + h * 128;
            const float* ad = att_dst + h * 128;
            for (int c = 0; c < 128; ++c) {
                float w = wr[c];
                s = fmaf(w, as[c], s);
                d = fmaf(w, ad[c], d);
            }
            vas[k * 4 + h] = s;
            vad[k * 4 + h] = d;
        }
    } else {
        int i = (b - 161) * 256 + tid;
        if (i < N_NODES) deg[i] = 0;
    }
}

// ---------------------------------------------------------------------------
// LDS-pipelined split-bf16 GEMM (packed B), fp32 A — proj (K=768), gat2 (K=512)
// ATTH: 0=no fused logits; 4=write a1s/a1d (H=4, z==0 only); 1=write a2s/a2d.
// ---------------------------------------------------------------------------
template<int K, int SRCSEL, int ZC, int ACT, int LDOUT, int ATTH>
__global__ __launch_bounds__(256)
void mmT_kernel(const float* __restrict__ A0, const float* __restrict__ A1,
                size_t azs,
                const u16* __restrict__ Bh, const u16* __restrict__ Bl,
                const float* __restrict__ bias,
                float* __restrict__ out0, float* __restrict__ out1,
                const float* __restrict__ attVs, const float* __restrict__ attVd,
                float* __restrict__ attS, float* __restrict__ attD) {
    constexpr int NS = K / 64;
    __shared__ float smem[2 * 2080];
    __shared__ float ared[4][32][8];
    const int lane = threadIdx.x & 63;
    const int wid  = threadIdx.x >> 6;
    const int lr = lane & 15, q = lane >> 4;
    const int row0 = blockIdx.x * 32;
    const int z = blockIdx.z;
    const int gcb = blockIdx.y * 128 + z * ZC;

    const float* Ab = SRCSEL ? (z ? A1 : A0) : (A0 + (size_t)z * azs);
    float* outp = (SRCSEL && z) ? out1 : out0;

    const int srow = min(row0 + (lane >> 1), N_NODES - 1);
    const float* sA = Ab + (size_t)srow * K + (lane & 1) * 4;
    float* dg0 = smem + (wid * 2 + 0) * 260;
    float* dg1 = smem + (wid * 2 + 1) * 260;

    const int cg = gcb / 32 + wid;
    const u16* pbh = Bh + (size_t)cg * K * 32 + lane * 8;
    const u16* pbl = Bl + (size_t)cg * K * 32 + lane * 8;

    f32x4 acc[2][2];
#pragma unroll
    for (int i = 0; i < 2; ++i)
#pragma unroll
        for (int j = 0; j < 2; ++j) acc[i][j] = (f32x4){0.f, 0.f, 0.f, 0.f};

    bf16x8 rbh[2][2][2], rbl[2][2][2];

#define STAGE_T(BUF, S) do {                                                   \
        GLD16(sA + (S) * 64 + (wid * 2 + 0) * 8, dg0 + (BUF) * 2080);          \
        GLD16(sA + (S) * 64 + (wid * 2 + 1) * 8, dg1 + (BUF) * 2080);          \
    } while (0)

    STAGE_T(0, 0);
#pragma unroll
    for (int fn = 0; fn < 2; ++fn)
#pragma unroll
        for (int ks = 0; ks < 2; ++ks) {
            rbh[0][fn][ks] = *(const bf16x8*)(pbh + (ks * 2 + fn) * 512);
            rbl[0][fn][ks] = *(const bf16x8*)(pbl + (ks * 2 + fn) * 512);
        }
    __syncthreads();

#pragma unroll
    for (int s = 0; s < NS; ++s) {
        const int bank = s & 1;
        if (s + 1 < NS) {
            STAGE_T(bank ^ 1, s + 1);
#pragma unroll
            for (int fn = 0; fn < 2; ++fn)
#pragma unroll
                for (int ks = 0; ks < 2; ++ks) {
                    rbh[bank ^ 1][fn][ks] =
                        *(const bf16x8*)(pbh + (((s + 1) * 2 + ks) * 2 + fn) * 512);
                    rbl[bank ^ 1][fn][ks] =
                        *(const bf16x8*)(pbl + (((s + 1) * 2 + ks) * 2 + fn) * 512);
                }
        }
        const float* lb = smem + bank * 2080;
        bf16x8 ah[2][2], al[2][2];
#pragma unroll
        for (int fm = 0; fm < 2; ++fm)
#pragma unroll
            for (int ks = 0; ks < 2; ++ks) {
                const float* fp = lb + (ks * 4 + q) * 260 + (fm * 16 + lr) * 8;
                splitA8(fp, ah[fm][ks], al[fm][ks]);
            }
#pragma unroll
        for (int fm = 0; fm < 2; ++fm)
#pragma unroll
            for (int fn = 0; fn < 2; ++fn)
#pragma unroll
                for (int ks = 0; ks < 2; ++ks) {
                    MFMA3(ah[fm][ks], al[fm][ks],
                          rbh[bank][fn][ks], rbl[bank][fn][ks], acc[fm][fn]);
                }
        __syncthreads();
    }

    // epilogue: rv = acc + bias (pre-activation), store, then fused logits
    float rv[2][2][4];
    int orq = q * 4;
#pragma unroll
    for (int fm = 0; fm < 2; ++fm)
#pragma unroll
        for (int fn = 0; fn < 2; ++fn) {
            int col = gcb + wid * 32 + fn * 16 + lr;
            float bb = bias ? bias[col] : 0.0f;
#pragma unroll
            for (int i = 0; i < 4; ++i) {
                float r = acc[fm][fn][i] + bb;
                rv[fm][fn][i] = r;
                int orow = row0 + fm * 16 + orq + i;
                if (orow < N_NODES) {
                    if (ACT == 1) r = r > 0.0f ? r : expm1f(r);
                    outp[(size_t)orow * LDOUT + col] = r;
                }
            }
        }

    if (ATTH == 4) {
        if (z == 0) {
            const float4 vs0 = *reinterpret_cast<const float4*>(attVs + (wid * 32 + lr) * 4);
            const float4 vs1 = *reinterpret_cast<const float4*>(attVs + (wid * 32 + 16 + lr) * 4);
            const float4 vd0 = *reinterpret_cast<const float4*>(attVd + (wid * 32 + lr) * 4);
            const float4 vd1 = *reinterpret_cast<const float4*>(attVd + (wid * 32 + 16 + lr) * 4);
#pragma unroll
            for (int fm = 0; fm < 2; ++fm)
#pragma unroll
                for (int i = 0; i < 4; ++i) {
                    float r0 = rv[fm][0][i], r1 = rv[fm][1][i];
                    float ps[4] = { r0 * vs0.x + r1 * vs1.x, r0 * vs0.y + r1 * vs1.y,
                                    r0 * vs0.z + r1 * vs1.z, r0 * vs0.w + r1 * vs1.w };
                    float pd[4] = { r0 * vd0.x + r1 * vd1.x, r0 * vd0.y + r1 * vd1.y,
                                    r0 * vd0.z + r1 * vd1.z, r0 * vd0.w + r1 * vd1.w };
#pragma unroll
                    for (int m = 1; m < 16; m <<= 1)
#pragma unroll
                        for (int h = 0; h < 4; ++h) {
                            ps[h] += __shfl_xor(ps[h], m, 64);
                            pd[h] += __shfl_xor(pd[h], m, 64);
                        }
                    if (lr == 0) {
                        int rloc = fm * 16 + orq + i;
#pragma unroll
                        for (int h = 0; h < 4; ++h) {
                            ared[wid][rloc][h]     = ps[h];
                            ared[wid][rloc][4 + h] = pd[h];
                        }
                    }
                }
            __syncthreads();
            int rloc = threadIdx.x >> 3, sl = threadIdx.x & 7;
            float v = ared[0][rloc][sl] + ared[1][rloc][sl] +
                      ared[2][rloc][sl] + ared[3][rloc][sl];
            int orow = row0 + rloc;
            if (orow < N_NODES) {
                if (sl < 4) attS[(size_t)orow * 4 + sl] = v;
                else        attD[(size_t)orow * 4 + (sl - 4)] = v;
            }
        }
    } else if (ATTH == 1) {
        float vs0 = attVs[wid * 32 + lr], vs1 = attVs[wid * 32 + 16 + lr];
        float vd0 = attVd[wid * 32 + lr], vd1 = attVd[wid * 32 + 16 + lr];
#pragma unroll
        for (int fm = 0; fm < 2; ++fm)
#pragma unroll
            for (int i = 0; i < 4; ++i) {
                float r0 = rv[fm][0][i], r1 = rv[fm][1][i];
                float ps = r0 * vs0 + r1 * vs1;
                float pd = r0 * vd0 + r1 * vd1;
#pragma unroll
                for (int m = 1; m < 16; m <<= 1) {
                    ps += __shfl_xor(ps, m, 64);
                    pd += __shfl_xor(pd, m, 64);
                }
                if (lr == 0) {
                    int rloc = fm * 16 + orq + i;
                    ared[wid][rloc][0] = ps;
                    ared[wid][rloc][1] = pd;
                }
            }
        __syncthreads();
        if (threadIdx.x < 64) {
            int rloc = threadIdx.x >> 1, sl = threadIdx.x & 1;
            float v = ared[0][rloc][sl] + ared[1][rloc][sl] +
                      ared[2][rloc][sl] + ared[3][rloc][sl];
            int orow = row0 + rloc;
            if (orow < N_NODES) {
                if (sl == 0) attS[orow] = v;
                else         attD[orow] = v;
            }
        }
    }
#undef STAGE_T
}

// ---------------------------------------------------------------------------
// Barrier-free packed-A / packed-B GEMM, K=128 (mm_head & decoder).
// ---------------------------------------------------------------------------
template<int ZC, int ACT, int LDOUT>
__global__ __launch_bounds__(256)
void mmP_kernel(const u16* __restrict__ Ah, const u16* __restrict__ Al,
                size_t azs,
                const u16* __restrict__ Bh, const u16* __restrict__ Bl,
                const float* __restrict__ bias,
                float* __restrict__ out) {
    constexpr int K = 128;
    const int lane = threadIdx.x & 63;
    const int wid  = threadIdx.x >> 6;
    const int lr = lane & 15, q = lane >> 4;
    const int rg = blockIdx.x;
    const int row0 = rg * 32;
    const int z = blockIdx.z;
    const int gcb = blockIdx.y * 128 + z * ZC;

    const u16* ah = Ah + (size_t)z * azs + (size_t)rg * 4096 + lane * 8;
    const u16* al = Al + (size_t)z * azs + (size_t)rg * 4096 + lane * 8;
    const int cg = gcb / 32 + wid;
    const u16* bh = Bh + (size_t)cg * K * 32 + lane * 8;
    const u16* bl = Bl + (size_t)cg * K * 32 + lane * 8;

    f32x4 acc[2][2];
#pragma unroll
    for (int i = 0; i < 2; ++i)
#pragma unroll
        for (int j = 0; j < 2; ++j) acc[i][j] = (f32x4){0.f, 0.f, 0.f, 0.f};

#pragma unroll
    for (int kb = 0; kb < 4; ++kb) {
        bf16x8 a0h = *(const bf16x8*)(ah + (kb * 2 + 0) * 512);
        bf16x8 a1h = *(const bf16x8*)(ah + (kb * 2 + 1) * 512);
        bf16x8 a0l = *(const bf16x8*)(al + (kb * 2 + 0) * 512);
        bf16x8 a1l = *(const bf16x8*)(al + (kb * 2 + 1) * 512);
        bf16x8 b0h = *(const bf16x8*)(bh + (kb * 2 + 0) * 512);
        bf16x8 b1h = *(const bf16x8*)(bh + (kb * 2 + 1) * 512);
        bf16x8 b0l = *(const bf16x8*)(bl + (kb * 2 + 0) * 512);
        bf16x8 b1l = *(const bf16x8*)(bl + (kb * 2 + 1) * 512);
        MFMA3(a0h, a0l, b0h, b0l, acc[0][0]);
        MFMA3(a0h, a0l, b1h, b1l, acc[0][1]);
        MFMA3(a1h, a1l, b0h, b0l, acc[1][0]);
        MFMA3(a1h, a1l, b1h, b1l, acc[1][1]);
    }

    int orq = q * 4;
#pragma unroll
    for (int fm = 0; fm < 2; ++fm)
#pragma unroll
        for (int fn = 0; fn < 2; ++fn) {
            int col = gcb + wid * 32 + fn * 16 + lr;
            float bb = bias[col];
#pragma unroll
            for (int i = 0; i < 4; ++i) {
                int orow = row0 + fm * 16 + orq + i;
                if (orow < N_NODES) {
                    float r = acc[fm][fn][i] + bb;
                    if (ACT == 1) r = r > 0.0f ? r : expm1f(r);
                    out[(size_t)orow * LDOUT + col] = r;
                }
            }
        }
}

// ---------------------------------------------------------------------------
// CSR build
// ---------------------------------------------------------------------------
__global__ void deg_kernel(const int* __restrict__ ei, int* __restrict__ deg) {
    int e = blockIdx.x * blockDim.x + threadIdx.x;
    if (e >= ET) return;
    int d = (e < N_EDGES) ? ei[N_EDGES + e] : (e - N_EDGES);
    atomicAdd(&deg[d], 1);
}

__global__ void scan1_kernel(const int* __restrict__ deg, int* __restrict__ bsum) {
    __shared__ int sm[256];
    int i = blockIdx.x * 256 + threadIdx.x;
    sm[threadIdx.x] = (i < N_NODES) ? deg[i] : 0;
    __syncthreads();
    for (int s = 128; s > 0; s >>= 1) {
        if (threadIdx.x < s) sm[threadIdx.x] += sm[threadIdx.x + s];
        __syncthreads();
    }
    if (threadIdx.x == 0) bsum[blockIdx.x] = sm[0];
}

__global__ void scan3_kernel(const int* __restrict__ deg, const int* __restrict__ bsum,
                             int* __restrict__ off, int* __restrict__ cur) {
    __shared__ int sm[256];
    __shared__ int sb[40];
    __shared__ int bofs;
    int tid = threadIdx.x;
    if (tid < 40) sb[tid] = bsum[tid];
    int i = blockIdx.x * 256 + tid;
    int v = (i < N_NODES) ? deg[i] : 0;
    sm[tid] = v;
    __syncthreads();
    if (tid == 0) {
        int s = 0;
        for (int b = 0; b < blockIdx.x; ++b) s += sb[b];
        bofs = s;
    }
    for (int s = 1; s < 256; s <<= 1) {
        int t = (tid >= s) ? sm[tid - s] : 0;
        __syncthreads();
        sm[tid] += t;
        __syncthreads();
    }
    if (i < N_NODES) {
        int ex = bofs + sm[tid] - v;
        off[i] = ex;
        cur[i] = ex;
    }
    if (blockIdx.x == 0 && tid == 0) off[N_NODES] = ET;
}

__global__ void fill_kernel(const int* __restrict__ ei,
                            int* __restrict__ cur, int* __restrict__ csr_src) {
    int e = blockIdx.x * blockDim.x + threadIdx.x;
    if (e >= ET) return;
    int s, d;
    if (e < N_EDGES) { s = ei[e]; d = ei[N_EDGES + e]; }
    else             { s = e - N_EDGES; d = s; }
    int pos = atomicAdd(&cur[d], 1);
    csr_src[pos] = s;
}

// ---------------------------------------------------------------------------
// Fused softmax + aggregation, layer 1 (H=4), SINGLE PASS.
// ---------------------------------------------------------------------------
__global__ __launch_bounds__(128)
void smagg1_kernel(const float* __restrict__ xp,
                   const float* __restrict__ a1s, const float* __restrict__ a1d,
                   const int* __restrict__ off, const int* __restrict__ csr,
                   u16* __restrict__ aggPh, u16* __restrict__ aggPl) {
    int n = blockIdx.x;
    int tid = threadIdx.x;
    int o0 = off[n], o1 = off[n + 1];
    __shared__ float wsh[128][4];
    __shared__ int   ssh[128];

    float4 adv = *reinterpret_cast<const float4*>(a1d + (size_t)n * 4);
    float adn[4] = {adv.x, adv.y, adv.z, adv.w};

    float a0 = 0.f, a1 = 0.f, a2 = 0.f, a3 = 0.f;
    float s0 = 0.f, s1 = 0.f, s2 = 0.f, s3 = 0.f;
    for (int base = o0; base < o1; base += 128) {
        __syncthreads();
        int j = base + tid;
        if (j < o1) {
            int sn = csr[j];
            ssh[tid] = sn;
            float4 asv = *reinterpret_cast<const float4*>(a1s + (size_t)sn * 4);
            float e0 = asv.x + adn[0]; e0 = e0 > 0.f ? e0 : 0.2f * e0; wsh[tid][0] = expf(e0);
            float e1 = asv.y + adn[1]; e1 = e1 > 0.f ? e1 : 0.2f * e1; wsh[tid][1] = expf(e1);
            float e2 = asv.z + adn[2]; e2 = e2 > 0.f ? e2 : 0.2f * e2; wsh[tid][2] = expf(e2);
            float e3 = asv.w + adn[3]; e3 = e3 > 0.f ? e3 : 0.2f * e3; wsh[tid][3] = expf(e3);
        }
        __syncthreads();
        int cnt = min(128, o1 - base);
        for (int e2i = 0; e2i < cnt; ++e2i) {
            float v = xp[(size_t)ssh[e2i] * 128 + tid];
            float4 w = *reinterpret_cast<const float4*>(&wsh[e2i][0]);
            a0 = fmaf(w.x, v, a0); s0 += w.x;
            a1 = fmaf(w.y, v, a1); s1 += w.y;
            a2 = fmaf(w.z, v, a2); s2 += w.z;
            a3 = fmaf(w.w, v, a3); s3 += w.w;
        }
    }

    float r[4] = {a0 / (s0 + 1e-16f), a1 / (s1 + 1e-16f),
                  a2 / (s2 + 1e-16f), a3 / (s3 + 1e-16f)};
    size_t po = packA_off(n, tid);
#pragma unroll
    for (int h = 0; h < 4; ++h) {
        u16 hi, lo;
        split1(r[h], hi, lo);
        aggPh[(size_t)h * AZS + po] = hi;
        aggPl[(size_t)h * AZS + po] = lo;
    }
}

// ---------------------------------------------------------------------------
// Fused softmax + gather, layer 2 (H=1), SINGLE PASS, + bias + beta*gp.
// ---------------------------------------------------------------------------
__global__ __launch_bounds__(128)
void smgather2_kernel(const float* __restrict__ h2,
                      const float* __restrict__ a2s, const float* __restrict__ a2d,
                      const int* __restrict__ off, const int* __restrict__ csr,
                      const float* __restrict__ bias,
                      u16* __restrict__ outPh, u16* __restrict__ outPl,
                      const float* __restrict__ gp,
                      const float* __restrict__ beta_p) {
    int n = blockIdx.x;
    int tid = threadIdx.x;
    int o0 = off[n], o1 = off[n + 1];
    __shared__ float wsh[128];
    __shared__ int   ssh[128];

    float adn = a2d[n];
    float acc = 0.f, s = 0.f;
    for (int base = o0; base < o1; base += 128) {
        __syncthreads();
        int j = base + tid;
        if (j < o1) {
            int sn = csr[j];
            ssh[tid] = sn;
            float e = a2s[sn] + adn;
            e = e > 0.f ? e : 0.2f * e;
            wsh[tid] = expf(e);
        }
        __syncthreads();
        int cnt = min(128, o1 - base);
        for (int e2i = 0; e2i < cnt; ++e2i) {
            float w = wsh[e2i];
            acc = fmaf(w, h2[(size_t)ssh[e2i] * 128 + tid], acc);
            s += w;
        }
    }

    float r = acc / (s + 1e-16f) + bias[tid] + beta_p[0] * gp[(size_t)n * 128 + tid];
    u16 hi, lo;
    split1(r, hi, lo);
    size_t po = packA_off(n, tid);
    outPh[po] = hi;
    outPl[po] = lo;
}

// ---------------------------------------------------------------------------
extern "C" void kernel_launch(void* const* d_in, const int* in_sizes, int n_in,
                              void* d_out, int out_size, void* d_ws, size_t ws_size,
                              hipStream_t stream) {
    const float* x      = (const float*)d_in[0];
    const int*   ei     = (const int*)  d_in[1];
    const float* g      = (const float*)d_in[2];
    const float* proj_W = (const float*)d_in[3];
    const float* proj_b = (const float*)d_in[4];
    const float* gat1_W = (const float*)d_in[5];
    const float* g1_as  = (const float*)d_in[6];
    const float* g1_ad  = (const float*)d_in[7];
    const float* gat1_b = (const float*)d_in[8];
    const float* gat2_W = (const float*)d_in[9];
    const float* g2_as  = (const float*)d_in[10];
    const float* g2_ad  = (const float*)d_in[11];
    const float* gat2_b = (const float*)d_in[12];
    const float* dec_W  = (const float*)d_in[13];
    const float* dec_b  = (const float*)d_in[14];
    const float* beta   = (const float*)d_in[15];
    float* out = (float*)d_out;

    // ---- workspace carve ----
    char* p = (char*)d_ws;
    auto alloc = [&](size_t b) { void* r = (void*)p; p += (b + 255) & ~(size_t)255; return r; };
    float* helu  = (float*)alloc((size_t)10000 * 512 * 4);
    u16*   aggPh = (u16*)alloc(4 * AZS * 2);
    u16*   aggPl = (u16*)alloc(4 * AZS * 2);
    u16*   hfPh  = (u16*)alloc(AZS * 2);
    u16*   hfPl  = (u16*)alloc(AZS * 2);
    float* xp    = (float*)alloc((size_t)10000 * 128 * 4);     // h2 alias
    float* gp    = (float*)alloc((size_t)10000 * 128 * 4);
    u16*   pwh   = (u16*)alloc(768 * 128 * 2);
    u16*   pwl   = (u16*)alloc(768 * 128 * 2);
    u16*   w1h   = (u16*)alloc(128 * 512 * 2);
    u16*   w1l   = (u16*)alloc(128 * 512 * 2);
    u16*   w2h   = (u16*)alloc(512 * 128 * 2);
    u16*   w2l   = (u16*)alloc(512 * 128 * 2);
    u16*   wdh   = (u16*)alloc(128 * 768 * 2);
    u16*   wdl   = (u16*)alloc(128 * 768 * 2);
    float* va1s  = (float*)alloc(128 * 4 * 4);
    float* va1d  = (float*)alloc(128 * 4 * 4);
    float* a1s   = (float*)alloc((size_t)N_NODES * 4 * 4);
    float* a1d   = (float*)alloc((size_t)N_NODES * 4 * 4);
    float* a2s   = (float*)alloc((size_t)N_NODES * 4);
    float* a2d   = (float*)alloc((size_t)N_NODES * 4);
    int*   deg   = (int*)alloc((size_t)N_NODES * 4);
    int*   off   = (int*)alloc((size_t)(N_NODES + 1) * 4);
    int*   cur   = (int*)alloc((size_t)N_NODES * 4);
    int*   csr   = (int*)alloc((size_t)ET * 4);
    int*   bsum  = (int*)alloc(64 * 4);
    // aliases
    float* h2 = xp;

    // ---- fused prep (wpack + va1 + deg zero) ----
    hipLaunchKernelGGL(prep_kernel, dim3(201), dim3(256), 0, stream,
                       proj_W, pwh, pwl, gat1_W, w1h, w1l,
                       gat2_W, w2h, w2l, dec_W, wdh, wdl,
                       g1_as, g1_ad, va1s, va1d, deg);
    hipLaunchKernelGGL(deg_kernel, dim3((ET + 255) / 256), dim3(256), 0, stream, ei, deg);
    hipLaunchKernelGGL(scan1_kernel, dim3(40), dim3(256), 0, stream, deg, bsum);
    hipLaunchKernelGGL(scan3_kernel, dim3(40), dim3(256), 0, stream, deg, bsum, off, cur);
    hipLaunchKernelGGL(fill_kernel, dim3((ET + 255) / 256), dim3(256), 0, stream, ei, cur, csr);

    // ---- proj: xp = x@Wp+b, gp = g@Wp+b; logits a1s/a1d fused (z==0) ----
    hipLaunchKernelGGL((mmT_kernel<768, 1, 0, 0, 128, 4>), dim3(NRG, 1, 2), dim3(256), 0, stream,
                       x, g, (size_t)0, pwh, pwl, proj_b, xp, gp,
                       va1s, va1d, a1s, a1d);

    // ---- gat1 ----
    hipLaunchKernelGGL(smagg1_kernel, dim3(N_NODES), dim3(128), 0, stream,
                       xp, a1s, a1d, off, csr, aggPh, aggPl);
    hipLaunchKernelGGL((mmP_kernel<128, 1, 512>), dim3(NRG, 1, 4), dim3(256), 0, stream,
                       aggPh, aggPl, AZS, w1h, w1l, gat1_b, helu);

    // ---- gat2: h2 = helu @ W2; logits a2s/a2d fused ----
    hipLaunchKernelGGL((mmT_kernel<512, 0, 0, 0, 128, 1>), dim3(NRG, 1, 1), dim3(256), 0, stream,
                       helu, (const float*)nullptr, (size_t)0,
                       w2h, w2l, (const float*)nullptr, h2, (float*)nullptr,
                       g2_as, g2_ad, a2s, a2d);
    hipLaunchKernelGGL(smgather2_kernel, dim3(N_NODES), dim3(128), 0, stream,
                       h2, a2s, a2d, off, csr, gat2_b, hfPh, hfPl, gp, beta);

    // ---- decoder ----
    hipLaunchKernelGGL((mmP_kernel<0, 0, 768>), dim3(NRG, 6, 1), dim3(256), 0, stream,
                       hfPh, hfPl, (size_t)0, wdh, wdl, dec_b, out);
}